// Round 14
// baseline (64.028 us; speedup 1.0000x reference)
//
#include <hip/hip_runtime.h>

// Involution fused kernels for MI355X (gfx950).
// x: (4,256,56,56) f32, w1: (64,256), bn(64), w2: (784,64), b2: (784)
// out: (4,256,56,56) f32
// ws: ybf16 [4][3136][64] | wprep bf16 [16][64][64] | b2pad f32 [16][64] | w1bf bf16 [64][256]

#define HW    3136
#define WIDE  56
#define C_IN  256
#define CR    64
#define GC    16
#define KK    49
#define BN_EPS 1e-5f

typedef __attribute__((ext_vector_type(8))) short short8;
typedef __attribute__((ext_vector_type(4))) float f32x4;
typedef __attribute__((ext_vector_type(2))) unsigned int u32x2;

__device__ __forceinline__ unsigned short f2bf(float f) {
    unsigned u = __float_as_uint(f);
    return (unsigned short)((u + 0x7FFFu + ((u >> 16) & 1u)) >> 16);   // RNE
}

// ---- Prep: w1bf[o][c] bf16; wprep[g][k][c] bf16 (k>=49 zero); b2pad[g][k] f32 ----
__global__ __launch_bounds__(256) void prep_kernel(
    const float* __restrict__ w1, const float* __restrict__ w2,
    const float* __restrict__ b2,
    unsigned short* __restrict__ w1bf, unsigned short* __restrict__ wprep,
    float* __restrict__ b2pad)
{
    const int t = blockIdx.x * 256 + threadIdx.x;   // 0..65535
    if (t < 16384) {                                // w1bf: same [o][c] layout
        w1bf[t] = f2bf(w1[t]);
    }
    {                                               // wprep: g=t>>12, k=(t>>6)&63, c=t&63
        const int g = t >> 12, k = (t >> 6) & 63, c = t & 63;
        wprep[t] = (k < KK) ? f2bf(w2[(size_t)(g * KK + k) * CR + c]) : (unsigned short)0;
    }
    if (t < 1024) {                                 // b2pad
        const int g = t >> 6, k = t & 63;
        b2pad[t] = (k < KK) ? b2[g * KK + k] : 0.f;
    }
}

// LDS xs[px][c] bf16, XOR-swizzled: byte = (px*512 + c*2) ^ ((px&7)<<4).
__device__ __forceinline__ int xs_byte(int px, int c) {
    return ((px << 9) + (c << 1)) ^ ((px & 7) << 4);
}

// ---- Kernel 1: y = relu(bn(w1 @ x)) -> bf16 [b][px][c], via MFMA (R11) ----
__global__ __launch_bounds__(256) void conv1_bn_relu(
    const float* __restrict__ x, const unsigned short* __restrict__ w1bf,
    const float* __restrict__ gamma, const float* __restrict__ beta,
    const float* __restrict__ mean, const float* __restrict__ var,
    unsigned short* __restrict__ ybf)
{
    __shared__ unsigned short xs[64 * 256];   // 32 KB

    const int t    = threadIdx.x;
    const int lane = t & 63;
    const int q    = __builtin_amdgcn_readfirstlane(t >> 6);  // wave 0..3
    const int tile = blockIdx.x;              // 0..195
    const int b    = tile / 49;
    const int hw0  = (tile - b * 49) * 64;

    // ---- stage x[b][c][hw0+lane] -> xs[lane][c] ----
    {
        const int px = lane;
        const int cb = q * 64;
        const float* __restrict__ xb = x + ((size_t)b * C_IN + cb) * HW + hw0 + px;
#pragma unroll
        for (int i = 0; i < 8; ++i) {
            short8 pk;
#pragma unroll
            for (int j = 0; j < 8; ++j)
                pk[j] = (short)f2bf(xb[(size_t)(i * 8 + j) * HW]);
            *(short8*)((char*)xs + xs_byte(px, cb + i * 8)) = pk;
        }
    }
    __syncthreads();

    // ---- MFMA: y[o][px] for px-quadrant q ----
    const int l15 = lane & 15;
    const int lg  = lane >> 4;
    const int px  = q * 16 + l15;

    f32x4 acc[4];
#pragma unroll
    for (int mt = 0; mt < 4; ++mt) acc[mt] = (f32x4){0.f, 0.f, 0.f, 0.f};

#pragma unroll
    for (int kk = 0; kk < 8; ++kk) {
        const short8 Bf = *(const short8*)((const char*)xs + xs_byte(px, kk * 32 + lg * 8));
#pragma unroll
        for (int mt = 0; mt < 4; ++mt) {
            const short8 Af = *(const short8*)(w1bf + (mt * 16 + l15) * C_IN + kk * 32 + lg * 8);
            acc[mt] = __builtin_amdgcn_mfma_f32_16x16x32_bf16(Af, Bf, acc[mt], 0, 0, 0);
        }
    }

    // ---- BN + ReLU + pack; D: col=l15 -> px, row=lg*4+r -> o ----
#pragma unroll
    for (int mt = 0; mt < 4; ++mt) {
        const int o0 = mt * 16 + lg * 4;
        const f32x4 ga = *(const f32x4*)(gamma + o0);
        const f32x4 be = *(const f32x4*)(beta + o0);
        const f32x4 mn = *(const f32x4*)(mean + o0);
        const f32x4 va = *(const f32x4*)(var + o0);
        unsigned short o4[4];
#pragma unroll
        for (int r = 0; r < 4; ++r) {
            const float sc = ga[r] * rsqrtf(va[r] + BN_EPS);
            const float sh = be[r] - mn[r] * sc;
            o4[r] = f2bf(fmaxf(acc[mt][r] * sc + sh, 0.f));
        }
        u32x2 pk;
        pk.x = (unsigned)o4[0] | ((unsigned)o4[1] << 16);
        pk.y = (unsigned)o4[2] | ((unsigned)o4[3] << 16);
        *(u32x2*)(ybf + ((size_t)(b * HW + hw0 + px)) * 64 + o0) = pk;
    }
}

// ---- Kernel 2: MFMA conv2 + LDS-staged involution. 128 thr / block. ----
// Block = (b, g, 64-px tile).
// STAGE: x[16ch][9 row-clamped rows] -> LDS xs[16][9][68] f32 (row layout
//   [4 zero-pad][56 data][4 zero-pad][4 dead]; ch-stride 612 f32 == 4 mod
//   32 banks -> quarter-wave ch groups hit different banks). Slot j holds
//   global row clamp(r0-3+j,0,55); window row for (hrow,i) = slot
//   (hrow-r0)+i whose content == clamp(hrow+i-3) EXACTLY as the old
//   clamped-global scheme. Zero pads are consumed only by kw==0 taps.
//   16 fully-coalesced dwordx4 loads/thread (was 84 scattered).
// Phase 1 (R10's validated 2-wave code): wave wv does px-quadrants
//   {wv, wv+2}; 8 MFMA each; bias, OOB-zero -> kw_lds[k][px].
// Phase 2: thread = (pg = tid&15 -> 4 px, cq = tid>>4 -> 2 ch). Per (i):
//   6 ds_read_b128 window + 7 ds_read_b128 kw (broadcast) + 56 FMA.
__global__ __launch_bounds__(128) void conv2_involution(
    const float* __restrict__ x, const unsigned short* __restrict__ ybf,
    const unsigned short* __restrict__ wprep, const float* __restrict__ b2pad,
    float* __restrict__ out)
{
    __shared__ float xs[16 * 612];      // 39168 B
    __shared__ float kw_lds[KK * 64];   // 12544 B

    const int tid  = threadIdx.x;       // 0..127
    const int tile = blockIdx.x;        // 0..48
    const int g    = blockIdx.y & 15;
    const int b    = blockIdx.y >> 4;
    const int r0   = (tile * 64) / WIDE;
    const int base_row = r0 - 3;

    // ---- STAGE: 2016 data f32x4 chunks, coalesced ----
    {
        const float* __restrict__ xg = x + ((size_t)b * C_IN + g * GC) * HW;
#pragma unroll
        for (int it = 0; it < 16; ++it) {
            const int id = it * 128 + tid;            // 0..2047
            if (id < 2016) {                          // c=id/126, j=rem/14, c4=rem%14
                const int c   = id / 126;
                const int rem = id - c * 126;
                const int j   = rem / 14;
                const int c4  = rem - j * 14;
                const int gr  = min(max(base_row + j, 0), WIDE - 1);
                const f32x4 v = *(const f32x4*)(xg + (size_t)c * HW + gr * WIDE + c4 * 4);
                *(f32x4*)&xs[c * 612 + j * 68 + 4 + c4 * 4] = v;
            }
        }
        // zero side pads: 288 chunks
#pragma unroll
        for (int it = 0; it < 3; ++it) {
            const int p = it * 128 + tid;
            if (p < 288) {
                const int c    = p / 18;
                const int rem  = p - c * 18;
                const int j    = rem >> 1;
                const int side = rem & 1;
                *(f32x4*)&xs[c * 612 + j * 68 + (side ? 60 : 0)] = (f32x4){0.f, 0.f, 0.f, 0.f};
            }
        }
    }

    // ---- Phase 1: kw = W2g @ y; wave wv does quadrants {wv, wv+2} ----
    {
        const int lane = tid & 63;
        const int wv   = __builtin_amdgcn_readfirstlane(tid >> 6);  // 0..1
        const int l15  = lane & 15;
        const int lg   = lane >> 4;
#pragma unroll
        for (int cti = 0; cti < 2; ++cti) {
            const int ct  = wv + cti * 2;
            const int px  = ct * 16 + l15;
            const int hwp = tile * 64 + px;
            const unsigned short* yb = ybf + ((size_t)(b * HW + hwp)) * 64 + lg * 8;
            const short8 B0 = *(const short8*)(yb);
            const short8 B1 = *(const short8*)(yb + 32);
            const int hp = hwp / WIDE;
            const int wp = hwp - hp * WIDE;

#pragma unroll
            for (int rt = 0; rt < 4; ++rt) {
                const unsigned short* ar = wprep + g * 4096 + (rt * 16 + l15) * 64 + lg * 8;
                const short8 A0 = *(const short8*)(ar);
                const short8 A1 = *(const short8*)(ar + 32);
                f32x4 acc = (f32x4){0.f, 0.f, 0.f, 0.f};
                acc = __builtin_amdgcn_mfma_f32_16x16x32_bf16(A0, B0, acc, 0, 0, 0);
                acc = __builtin_amdgcn_mfma_f32_16x16x32_bf16(A1, B1, acc, 0, 0, 0);
#pragma unroll
                for (int r = 0; r < 4; ++r) {
                    const int k = rt * 16 + lg * 4 + r;
                    if (k < KK) {
                        const float val = acc[r] + b2pad[g * 64 + k];
                        const int i7 = k / 7, j7 = k - i7 * 7;
                        const int rr = hp + i7 - 3, cc = wp + j7 - 3;
                        const bool valid = (rr >= 0) & (rr < WIDE) &
                                           (cc >= 0) & (cc < WIDE);
                        kw_lds[k * 64 + px] = valid ? val : 0.f;
                    }
                }
            }
        }
    }
    __syncthreads();

    // ---- Phase 2: involution from LDS, 4 px x 2 ch per thread ----
    const int pg   = tid & 15;
    const int cq   = tid >> 4;                   // 0..7 -> ch cq*2, cq*2+1
    const int hw4  = tile * 64 + pg * 4;
    const int hrow = hw4 / WIDE;
    const int hcol = hw4 - hrow * WIDE;          // 4-aligned
    const int srow = hrow - r0;                  // 0..2

    const int xb0 = (cq * 2) * 612 + srow * 68 + hcol;   // pad-rel col hcol

    float acc2[2][4];
#pragma unroll
    for (int c = 0; c < 2; ++c)
#pragma unroll
        for (int p = 0; p < 4; ++p) acc2[c][p] = 0.f;

#pragma unroll
    for (int i = 0; i < 7; ++i) {
        const int rb0 = xb0 + i * 68;
        const int rb1 = rb0 + 612;

        float win[2][12];
        {
            const f32x4 A0 = *(const f32x4*)&xs[rb0];
            const f32x4 A1 = *(const f32x4*)&xs[rb0 + 4];
            const f32x4 A2 = *(const f32x4*)&xs[rb0 + 8];
            const f32x4 B0 = *(const f32x4*)&xs[rb1];
            const f32x4 B1 = *(const f32x4*)&xs[rb1 + 4];
            const f32x4 B2 = *(const f32x4*)&xs[rb1 + 8];
#pragma unroll
            for (int e = 0; e < 4; ++e) {
                win[0][e]     = A0[e];
                win[0][e + 4] = A1[e];
                win[0][e + 8] = A2[e];
                win[1][e]     = B0[e];
                win[1][e + 4] = B1[e];
                win[1][e + 8] = B2[e];
            }
        }
#pragma unroll
        for (int jj = 0; jj < 7; ++jj) {
            const f32x4 kw4 = *(const f32x4*)&kw_lds[(i * 7 + jj) * 64 + pg * 4];
#pragma unroll
            for (int c = 0; c < 2; ++c)
#pragma unroll
                for (int p = 0; p < 4; ++p)
                    acc2[c][p] += kw4[p] * win[c][p + jj + 1];
        }
    }

    f32x4 st0, st1;
#pragma unroll
    for (int p = 0; p < 4; ++p) { st0[p] = acc2[0][p]; st1[p] = acc2[1][p]; }
    float* __restrict__ ob = out + ((size_t)b * C_IN + g * GC + cq * 2) * HW + hw4;
    *(f32x4*)(ob)      = st0;
    *(f32x4*)(ob + HW) = st1;
}

extern "C" void kernel_launch(void* const* d_in, const int* in_sizes, int n_in,
                              void* d_out, int out_size, void* d_ws, size_t ws_size,
                              hipStream_t stream) {
    const float* x     = (const float*)d_in[0];
    const float* w1    = (const float*)d_in[1];
    const float* gamma = (const float*)d_in[2];
    const float* beta  = (const float*)d_in[3];
    const float* mean  = (const float*)d_in[4];
    const float* var   = (const float*)d_in[5];
    const float* w2    = (const float*)d_in[6];
    const float* b2    = (const float*)d_in[7];
    float* out = (float*)d_out;

    char* ws = (char*)d_ws;
    unsigned short* ybf   = (unsigned short*)(ws);             // 1,605,632 B
    unsigned short* wprep = (unsigned short*)(ws + 1605632);   //   131,072 B
    float*          b2pad = (float*)(ws + 1736704);            //     4,096 B
    unsigned short* w1bf  = (unsigned short*)(ws + 1740800);   //    32,768 B

    prep_kernel<<<dim3(256), dim3(256), 0, stream>>>(w1, w2, b2, w1bf, wprep, b2pad);
    conv1_bn_relu<<<dim3(196), dim3(256), 0, stream>>>(x, w1bf, gamma, beta, mean, var, ybf);
    conv2_involution<<<dim3(49, 64), dim3(128), 0, stream>>>(x, ybf, wprep, b2pad, out);
}

// Round 16
// 47.480 us; speedup vs baseline: 1.3485x; 1.3485x over previous
//
#include <hip/hip_runtime.h>

// Involution fused kernels for MI355X (gfx950).
// x: (4,256,56,56) f32, w1: (64,256), bn(64), w2: (784,64), b2: (784)
// out: (4,256,56,56) f32
// ws: ybf16 [4][3136][64] | wprep bf16 [16][64][64] | b2pad f32 [16][64] |
//     w1bf bf16 [64][256] | xbf bf16 [1024 planes][62][64] (zero-padded)

#define HW    3136
#define WIDE  56
#define C_IN  256
#define CR    64
#define GC    16
#define KK    49
#define BN_EPS 1e-5f
#define PROW  62
#define PCOL  64
#define PSTR  (PROW * PCOL)   // 3968 elems per padded plane

typedef __attribute__((ext_vector_type(8))) short short8;
typedef __attribute__((ext_vector_type(4))) short s16x4;
typedef __attribute__((ext_vector_type(4))) float f32x4;
typedef __attribute__((ext_vector_type(2))) unsigned int u32x2;

__device__ __forceinline__ unsigned short f2bf(float f) {
    unsigned u = __float_as_uint(f);
    return (unsigned short)((u + 0x7FFFu + ((u >> 16) & 1u)) >> 16);   // RNE
}
__device__ __forceinline__ float bf2f(unsigned short v) {
    return __uint_as_float(((unsigned)v) << 16);
}

// ---- Prep: w1bf[o][c] bf16; wprep[g][k][c] bf16 (k>=49 zero); b2pad[g][k] f32 ----
__global__ __launch_bounds__(256) void prep_kernel(
    const float* __restrict__ w1, const float* __restrict__ w2,
    const float* __restrict__ b2,
    unsigned short* __restrict__ w1bf, unsigned short* __restrict__ wprep,
    float* __restrict__ b2pad)
{
    const int t = blockIdx.x * 256 + threadIdx.x;   // 0..65535
    if (t < 16384) {                                // w1bf: same [o][c] layout
        w1bf[t] = f2bf(w1[t]);
    }
    {                                               // wprep: g=t>>12, k=(t>>6)&63, c=t&63
        const int g = t >> 12, k = (t >> 6) & 63, c = t & 63;
        wprep[t] = (k < KK) ? f2bf(w2[(size_t)(g * KK + k) * CR + c]) : (unsigned short)0;
    }
    if (t < 1024) {                                 // b2pad
        const int g = t >> 6, k = t & 63;
        b2pad[t] = (k < KK) ? b2[g * KK + k] : 0.f;
    }
}

// ---- xpad: zero-padded bf16 planes. Thread = one padded row (64 bf16). ----
// plane p (0..1023) = b*256+ch; prow 0..61; logical row = prow-3; cols:
// [4 zero][56 data][4 zero]. 63488 threads.
__global__ __launch_bounds__(256) void xpad_kernel(
    const float* __restrict__ x, unsigned short* __restrict__ xbf)
{
    const int id = blockIdx.x * 256 + threadIdx.x;
    if (id >= 1024 * PROW) return;
    const int plane = id / PROW;
    const int prow  = id - plane * PROW;
    const int gr    = prow - 3;

    unsigned short row[PCOL];
    if (gr >= 0 && gr < WIDE) {
        const float* __restrict__ src = x + (size_t)plane * HW + gr * WIDE;
#pragma unroll
        for (int e = 0; e < 4; ++e) { row[e] = 0; row[60 + e] = 0; }
#pragma unroll
        for (int v = 0; v < 14; ++v) {
            const f32x4 a = *(const f32x4*)(src + v * 4);
#pragma unroll
            for (int e = 0; e < 4; ++e) row[4 + v * 4 + e] = f2bf(a[e]);
        }
    } else {
#pragma unroll
        for (int e = 0; e < PCOL; ++e) row[e] = 0;
    }

    unsigned short* __restrict__ dst = xbf + (size_t)plane * PSTR + prow * PCOL;
#pragma unroll
    for (int v = 0; v < 8; ++v)
        *(short8*)(dst + v * 8) = *(short8*)&row[v * 8];
}

// LDS xs[px][c] bf16, XOR-swizzled: byte = (px*512 + c*2) ^ ((px&7)<<4).
__device__ __forceinline__ int xs_byte(int px, int c) {
    return ((px << 9) + (c << 1)) ^ ((px & 7) << 4);
}

// ---- Kernel 1: y = relu(bn(w1 @ x)) -> bf16 [b][px][c], via MFMA (R11) ----
__global__ __launch_bounds__(256) void conv1_bn_relu(
    const float* __restrict__ x, const unsigned short* __restrict__ w1bf,
    const float* __restrict__ gamma, const float* __restrict__ beta,
    const float* __restrict__ mean, const float* __restrict__ var,
    unsigned short* __restrict__ ybf)
{
    __shared__ unsigned short xs[64 * 256];   // 32 KB

    const int t    = threadIdx.x;
    const int lane = t & 63;
    const int q    = __builtin_amdgcn_readfirstlane(t >> 6);  // wave 0..3
    const int tile = blockIdx.x;              // 0..195
    const int b    = tile / 49;
    const int hw0  = (tile - b * 49) * 64;

    // ---- stage x[b][c][hw0+lane] -> xs[lane][c] ----
    {
        const int px = lane;
        const int cb = q * 64;
        const float* __restrict__ xb = x + ((size_t)b * C_IN + cb) * HW + hw0 + px;
#pragma unroll
        for (int i = 0; i < 8; ++i) {
            short8 pk;
#pragma unroll
            for (int j = 0; j < 8; ++j)
                pk[j] = (short)f2bf(xb[(size_t)(i * 8 + j) * HW]);
            *(short8*)((char*)xs + xs_byte(px, cb + i * 8)) = pk;
        }
    }
    __syncthreads();

    // ---- MFMA: y[o][px] for px-quadrant q ----
    const int l15 = lane & 15;
    const int lg  = lane >> 4;
    const int px  = q * 16 + l15;

    f32x4 acc[4];
#pragma unroll
    for (int mt = 0; mt < 4; ++mt) acc[mt] = (f32x4){0.f, 0.f, 0.f, 0.f};

#pragma unroll
    for (int kk = 0; kk < 8; ++kk) {
        const short8 Bf = *(const short8*)((const char*)xs + xs_byte(px, kk * 32 + lg * 8));
#pragma unroll
        for (int mt = 0; mt < 4; ++mt) {
            const short8 Af = *(const short8*)(w1bf + (mt * 16 + l15) * C_IN + kk * 32 + lg * 8);
            acc[mt] = __builtin_amdgcn_mfma_f32_16x16x32_bf16(Af, Bf, acc[mt], 0, 0, 0);
        }
    }

    // ---- BN + ReLU + pack; D: col=l15 -> px, row=lg*4+r -> o ----
#pragma unroll
    for (int mt = 0; mt < 4; ++mt) {
        const int o0 = mt * 16 + lg * 4;
        const f32x4 ga = *(const f32x4*)(gamma + o0);
        const f32x4 be = *(const f32x4*)(beta + o0);
        const f32x4 mn = *(const f32x4*)(mean + o0);
        const f32x4 va = *(const f32x4*)(var + o0);
        unsigned short o4[4];
#pragma unroll
        for (int r = 0; r < 4; ++r) {
            const float sc = ga[r] * rsqrtf(va[r] + BN_EPS);
            const float sh = be[r] - mn[r] * sc;
            o4[r] = f2bf(fmaxf(acc[mt][r] * sc + sh, 0.f));
        }
        u32x2 pk;
        pk.x = (unsigned)o4[0] | ((unsigned)o4[1] << 16);
        pk.y = (unsigned)o4[2] | ((unsigned)o4[3] << 16);
        *(u32x2*)(ybf + ((size_t)(b * HW + hw0 + px)) * 64 + o0) = pk;
    }
}

// ---- Kernel 2: MFMA conv2 + involution from padded bf16 planes. ----
// Block = (b, g, 64-px tile), 64 threads (R11 grid; phase 1 identical).
// Phase 2 CHANGE: windows read from xbf padded planes: per (ch,row) 3 x
//   8B loads at compile-time offsets off one channel base (no clamps, no
//   per-load address math), unpack bf16->f32 via shl, then same FMA core.
//   Edge zeros come from the padding (kw-zeroing redundant but kept).
__global__ __launch_bounds__(64) void conv2_involution(
    const float* __restrict__ x, const unsigned short* __restrict__ ybf,
    const unsigned short* __restrict__ wprep, const float* __restrict__ b2pad,
    const unsigned short* __restrict__ xbf, float* __restrict__ out)
{
    __shared__ float kw_lds[64 * 64];   // [tap][px], 16 KB

    const int tid  = threadIdx.x;
    const int l15  = tid & 15;
    const int lg   = tid >> 4;
    const int tile = blockIdx.x;                 // 0..48
    const int g    = blockIdx.y & 15;
    const int b    = blockIdx.y >> 4;

    // ---- Phase 1: kw = W2g @ y  (per-pixel 64-tap kernels) ----
    {
        short8 Bf[4][2], Af[4][2];
#pragma unroll
        for (int ct = 0; ct < 4; ++ct) {
            const int hwp = tile * 64 + ct * 16 + l15;
            const unsigned short* yb = ybf + ((size_t)(b * HW + hwp)) * 64 + lg * 8;
            Bf[ct][0] = *(const short8*)(yb);
            Bf[ct][1] = *(const short8*)(yb + 32);
        }
#pragma unroll
        for (int rt = 0; rt < 4; ++rt) {
            const unsigned short* ar = wprep + g * 4096 + (rt * 16 + l15) * 64 + lg * 8;
            Af[rt][0] = *(const short8*)(ar);
            Af[rt][1] = *(const short8*)(ar + 32);
        }
        f32x4 acc[4][4];
#pragma unroll
        for (int ct = 0; ct < 4; ++ct)
#pragma unroll
            for (int rt = 0; rt < 4; ++rt) {
                acc[ct][rt] = (f32x4){0.f, 0.f, 0.f, 0.f};
                acc[ct][rt] = __builtin_amdgcn_mfma_f32_16x16x32_bf16(Af[rt][0], Bf[ct][0], acc[ct][rt], 0, 0, 0);
                acc[ct][rt] = __builtin_amdgcn_mfma_f32_16x16x32_bf16(Af[rt][1], Bf[ct][1], acc[ct][rt], 0, 0, 0);
            }

        float bias[4][4];
#pragma unroll
        for (int rt = 0; rt < 4; ++rt)
#pragma unroll
            for (int r = 0; r < 4; ++r)
                bias[rt][r] = b2pad[g * 64 + rt * 16 + lg * 4 + r];

#pragma unroll
        for (int ct = 0; ct < 4; ++ct) {
            const int pxc = ct * 16 + l15;
            const int hwp = tile * 64 + pxc;
            const int hp  = hwp / WIDE;
            const int wp  = hwp - hp * WIDE;
#pragma unroll
            for (int rt = 0; rt < 4; ++rt)
#pragma unroll
                for (int r = 0; r < 4; ++r) {
                    const int k  = rt * 16 + lg * 4 + r;
                    const int i7 = k / 7, j7 = k - i7 * 7;
                    const int rr = hp + i7 - 3, cc = wp + j7 - 3;
                    const bool valid = (k < KK) & (rr >= 0) & (rr < WIDE) &
                                       (cc >= 0) & (cc < WIDE);
                    kw_lds[k * 64 + pxc] = valid ? (acc[ct][rt][r] + bias[rt][r]) : 0.f;
                }
        }
    }
    __syncthreads();

    // ---- Phase 2: involution from padded bf16 planes, 4 px x 4 ch ----
    const int pg   = tid & 15;
    const int cq   = tid >> 4;
    const int hw4  = tile * 64 + pg * 4;         // 4-aligned flat pixel base
    const int hrow = hw4 / WIDE;
    const int hcol = hw4 - hrow * WIDE;          // 4-aligned

    // base elem in padded plane: row (hrow+i) at i=0 is padded-row hrow;
    // stored col hcol == logical col hcol-4 (window start).
    const int e0 = hrow * PCOL + hcol;
    const int pl0 = b * C_IN + g * GC + cq * 4;
    const char* pb[4];
#pragma unroll
    for (int c = 0; c < 4; ++c)
        pb[c] = (const char*)(xbf + (size_t)(pl0 + c) * PSTR + e0);

    float acc2[4][4];   // [ch][px]
#pragma unroll
    for (int c = 0; c < 4; ++c)
#pragma unroll
        for (int p = 0; p < 4; ++p) acc2[c][p] = 0.f;

#pragma unroll
    for (int i = 0; i < 7; ++i) {
        float win[4][12];
#pragma unroll
        for (int c = 0; c < 4; ++c) {
            const s16x4 s0 = *(const s16x4*)(pb[c] + i * 128 + 0);
            const s16x4 s1 = *(const s16x4*)(pb[c] + i * 128 + 8);
            const s16x4 s2 = *(const s16x4*)(pb[c] + i * 128 + 16);
#pragma unroll
            for (int e = 0; e < 4; ++e) {
                win[c][e]     = bf2f((unsigned short)s0[e]);
                win[c][e + 4] = bf2f((unsigned short)s1[e]);
                win[c][e + 8] = bf2f((unsigned short)s2[e]);
            }
        }
#pragma unroll
        for (int jj = 0; jj < 7; ++jj) {
            const f32x4 kw4 = *(const f32x4*)&kw_lds[(i * 7 + jj) * 64 + pg * 4];
#pragma unroll
            for (int c = 0; c < 4; ++c)
#pragma unroll
                for (int p = 0; p < 4; ++p)
                    acc2[c][p] += kw4[p] * win[c][p + jj + 1];   // logical col hcol+p+jj-3
        }
    }

#pragma unroll
    for (int c = 0; c < 4; ++c) {
        f32x4 st;
#pragma unroll
        for (int p = 0; p < 4; ++p) st[p] = acc2[c][p];
        *(f32x4*)(out + ((size_t)(pl0 + c)) * HW + hw4) = st;
    }
}

extern "C" void kernel_launch(void* const* d_in, const int* in_sizes, int n_in,
                              void* d_out, int out_size, void* d_ws, size_t ws_size,
                              hipStream_t stream) {
    const float* x     = (const float*)d_in[0];
    const float* w1    = (const float*)d_in[1];
    const float* gamma = (const float*)d_in[2];
    const float* beta  = (const float*)d_in[3];
    const float* mean  = (const float*)d_in[4];
    const float* var   = (const float*)d_in[5];
    const float* w2    = (const float*)d_in[6];
    const float* b2    = (const float*)d_in[7];
    float* out = (float*)d_out;

    char* ws = (char*)d_ws;
    unsigned short* ybf   = (unsigned short*)(ws);             // 1,605,632 B
    unsigned short* wprep = (unsigned short*)(ws + 1605632);   //   131,072 B
    float*          b2pad = (float*)(ws + 1736704);            //     4,096 B
    unsigned short* w1bf  = (unsigned short*)(ws + 1740800);   //    32,768 B
    unsigned short* xbf   = (unsigned short*)(ws + 1773568);   // 8,126,464 B

    prep_kernel<<<dim3(256), dim3(256), 0, stream>>>(w1, w2, b2, w1bf, wprep, b2pad);
    xpad_kernel<<<dim3(248), dim3(256), 0, stream>>>(x, xbf);
    conv1_bn_relu<<<dim3(196), dim3(256), 0, stream>>>(x, w1bf, gamma, beta, mean, var, ybf);
    conv2_involution<<<dim3(49, 64), dim3(64), 0, stream>>>(x, ybf, wprep, b2pad, xbf, out);
}

// Round 17
// 46.225 us; speedup vs baseline: 1.3851x; 1.0271x over previous
//
#include <hip/hip_runtime.h>

// Involution fused kernels for MI355X (gfx950).
// x: (4,256,56,56) f32, w1: (64,256), bn(64), w2: (784,64), b2: (784)
// out: (4,256,56,56) f32
// ws: ybf16 [4][3136][64] | wprep bf16 [16][64][64] | b2pad f32 [16][64] | w1bf bf16 [64][256]

#define HW    3136
#define WIDE  56
#define C_IN  256
#define CR    64
#define GC    16
#define KK    49
#define BN_EPS 1e-5f

typedef __attribute__((ext_vector_type(8))) short short8;
typedef __attribute__((ext_vector_type(4))) float f32x4;
typedef __attribute__((ext_vector_type(2))) unsigned int u32x2;

__device__ __forceinline__ unsigned short f2bf(float f) {
    unsigned u = __float_as_uint(f);
    return (unsigned short)((u + 0x7FFFu + ((u >> 16) & 1u)) >> 16);   // RNE
}

// ---- Prep: w1bf[o][c] bf16; wprep[g][k][c] bf16 (k>=49 zero); b2pad[g][k] f32 ----
__global__ __launch_bounds__(256) void prep_kernel(
    const float* __restrict__ w1, const float* __restrict__ w2,
    const float* __restrict__ b2,
    unsigned short* __restrict__ w1bf, unsigned short* __restrict__ wprep,
    float* __restrict__ b2pad)
{
    const int t = blockIdx.x * 256 + threadIdx.x;   // 0..65535
    if (t < 16384) {                                // w1bf: same [o][c] layout
        w1bf[t] = f2bf(w1[t]);
    }
    {                                               // wprep: g=t>>12, k=(t>>6)&63, c=t&63
        const int g = t >> 12, k = (t >> 6) & 63, c = t & 63;
        wprep[t] = (k < KK) ? f2bf(w2[(size_t)(g * KK + k) * CR + c]) : (unsigned short)0;
    }
    if (t < 1024) {                                 // b2pad
        const int g = t >> 6, k = t & 63;
        b2pad[t] = (k < KK) ? b2[g * KK + k] : 0.f;
    }
}

// LDS xs[px][c] bf16, XOR-swizzled: byte = (px*512 + c*2) ^ ((px&7)<<4).
__device__ __forceinline__ int xs_byte(int px, int c) {
    return ((px << 9) + (c << 1)) ^ ((px & 7) << 4);
}

// ---- Kernel 1: y = relu(bn(w1 @ x)) -> bf16 [b][px][c], via MFMA (R11) ----
__global__ __launch_bounds__(256) void conv1_bn_relu(
    const float* __restrict__ x, const unsigned short* __restrict__ w1bf,
    const float* __restrict__ gamma, const float* __restrict__ beta,
    const float* __restrict__ mean, const float* __restrict__ var,
    unsigned short* __restrict__ ybf)
{
    __shared__ unsigned short xs[64 * 256];   // 32 KB

    const int t    = threadIdx.x;
    const int lane = t & 63;
    const int q    = __builtin_amdgcn_readfirstlane(t >> 6);  // wave 0..3
    const int tile = blockIdx.x;              // 0..195
    const int b    = tile / 49;
    const int hw0  = (tile - b * 49) * 64;

    // ---- stage x[b][c][hw0+lane] -> xs[lane][c] ----
    {
        const int px = lane;
        const int cb = q * 64;
        const float* __restrict__ xb = x + ((size_t)b * C_IN + cb) * HW + hw0 + px;
#pragma unroll
        for (int i = 0; i < 8; ++i) {
            short8 pk;
#pragma unroll
            for (int j = 0; j < 8; ++j)
                pk[j] = (short)f2bf(xb[(size_t)(i * 8 + j) * HW]);
            *(short8*)((char*)xs + xs_byte(px, cb + i * 8)) = pk;
        }
    }
    __syncthreads();

    // ---- MFMA: y[o][px] for px-quadrant q ----
    const int l15 = lane & 15;
    const int lg  = lane >> 4;
    const int px  = q * 16 + l15;

    f32x4 acc[4];
#pragma unroll
    for (int mt = 0; mt < 4; ++mt) acc[mt] = (f32x4){0.f, 0.f, 0.f, 0.f};

#pragma unroll
    for (int kk = 0; kk < 8; ++kk) {
        const short8 Bf = *(const short8*)((const char*)xs + xs_byte(px, kk * 32 + lg * 8));
#pragma unroll
        for (int mt = 0; mt < 4; ++mt) {
            const short8 Af = *(const short8*)(w1bf + (mt * 16 + l15) * C_IN + kk * 32 + lg * 8);
            acc[mt] = __builtin_amdgcn_mfma_f32_16x16x32_bf16(Af, Bf, acc[mt], 0, 0, 0);
        }
    }

    // ---- BN + ReLU + pack; D: col=l15 -> px, row=lg*4+r -> o ----
#pragma unroll
    for (int mt = 0; mt < 4; ++mt) {
        const int o0 = mt * 16 + lg * 4;
        const f32x4 ga = *(const f32x4*)(gamma + o0);
        const f32x4 be = *(const f32x4*)(beta + o0);
        const f32x4 mn = *(const f32x4*)(mean + o0);
        const f32x4 va = *(const f32x4*)(var + o0);
        unsigned short o4[4];
#pragma unroll
        for (int r = 0; r < 4; ++r) {
            const float sc = ga[r] * rsqrtf(va[r] + BN_EPS);
            const float sh = be[r] - mn[r] * sc;
            o4[r] = f2bf(fmaxf(acc[mt][r] * sc + sh, 0.f));
        }
        u32x2 pk;
        pk.x = (unsigned)o4[0] | ((unsigned)o4[1] << 16);
        pk.y = (unsigned)o4[2] | ((unsigned)o4[3] << 16);
        *(u32x2*)(ybf + ((size_t)(b * HW + hw0 + px)) * 64 + o0) = pk;
    }
}

// ---- Kernel 2: MFMA conv2 + ROW-SPLIT involution. 256 thr / block. ----
// Block = (b, g, 64-px tile).
// Phase 1 (R9-validated): wave q computes kw for px-quadrant q via 8 MFMA.
// Phase 2 (NEW): wave w handles window rows i in {2w, 2w+1} (w=3: {6})
//   for the full 4px x 4ch per thread -> ONE load burst + ONE stall per
//   wave instead of 7 serial round-trips. Partials -> pacc (20-word
//   stride: 16B-aligned, bank-spread), cross-wave reduce by 256 threads.
// x addresses identical to R11 (clamped; garbage elems hit kw==0 only).
__global__ __launch_bounds__(256) void conv2_involution(
    const float* __restrict__ x, const unsigned short* __restrict__ ybf,
    const unsigned short* __restrict__ wprep, const float* __restrict__ b2pad,
    float* __restrict__ out)
{
    __shared__ float kw_lds[KK * 64];      // [tap][px], 12544 B
    __shared__ float pacc[4 * 64 * 20];    // [w][thr][c(4x f32x4 in 20 words)], 20480 B

    const int tid  = threadIdx.x;
    const int lane = tid & 63;
    const int w    = __builtin_amdgcn_readfirstlane(tid >> 6);  // wave 0..3
    const int l15  = lane & 15;
    const int lg   = lane >> 4;
    const int tile = blockIdx.x;                 // 0..48
    const int g    = blockIdx.y & 15;
    const int b    = blockIdx.y >> 4;

    // ---- Phase 1: kw = W2g @ y; wave w does px-quadrant w ----
    {
        const int px  = w * 16 + l15;
        const int hwp = tile * 64 + px;
        const unsigned short* yb = ybf + ((size_t)(b * HW + hwp)) * 64 + lg * 8;
        const short8 B0 = *(const short8*)(yb);
        const short8 B1 = *(const short8*)(yb + 32);
        const int hp = hwp / WIDE;
        const int wp = hwp - hp * WIDE;

#pragma unroll
        for (int rt = 0; rt < 4; ++rt) {
            const unsigned short* ar = wprep + g * 4096 + (rt * 16 + l15) * 64 + lg * 8;
            const short8 A0 = *(const short8*)(ar);
            const short8 A1 = *(const short8*)(ar + 32);
            f32x4 acc = (f32x4){0.f, 0.f, 0.f, 0.f};
            acc = __builtin_amdgcn_mfma_f32_16x16x32_bf16(A0, B0, acc, 0, 0, 0);
            acc = __builtin_amdgcn_mfma_f32_16x16x32_bf16(A1, B1, acc, 0, 0, 0);
#pragma unroll
            for (int r = 0; r < 4; ++r) {
                const int k = rt * 16 + lg * 4 + r;
                if (k < KK) {
                    const float val = acc[r] + b2pad[g * 64 + k];
                    const int i7 = k / 7, j7 = k - i7 * 7;
                    const int rr = hp + i7 - 3, cc = wp + j7 - 3;
                    const bool valid = (rr >= 0) & (rr < WIDE) &
                                       (cc >= 0) & (cc < WIDE);
                    kw_lds[k * 64 + px] = valid ? val : 0.f;
                }
            }
        }
    }
    __syncthreads();

    // ---- Phase 2: rows {2w, 2w+1} (w=3: {6}); 4px x 4ch per thread ----
    {
        const int pg   = lane & 15;
        const int cq   = lane >> 4;
        const int hw4  = tile * 64 + pg * 4;
        const int hrow = hw4 / WIDE;
        const int hcol = hw4 - hrow * WIDE;      // 4-aligned

        const float* bp[4];
#pragma unroll
        for (int c = 0; c < 4; ++c)
            bp[c] = x + ((size_t)b * C_IN + g * GC + cq * 4 + c) * HW;

        const int nr  = (w == 3) ? 1 : 2;
        const int i0r = 2 * w;

        // load burst: all rows' windows first (<=24 f32x4 in flight)
        f32x4 W[2][4][3];
#pragma unroll
        for (int ri = 0; ri < 2; ++ri) {
            if (ri < nr) {
                const int i     = i0r + ri;
                const int rc    = min(max(hrow + i - 3, 0), WIDE - 1);
                const int basef = rc * WIDE + hcol;
                const int i0 = max(basef - 4, 0);
                const int i2 = min(basef + 4, HW - 4);
#pragma unroll
                for (int c = 0; c < 4; ++c) {
                    W[ri][c][0] = *(const f32x4*)(bp[c] + i0);
                    W[ri][c][1] = *(const f32x4*)(bp[c] + basef);
                    W[ri][c][2] = *(const f32x4*)(bp[c] + i2);
                }
            }
        }

        float acc2[4][4];
#pragma unroll
        for (int c = 0; c < 4; ++c)
#pragma unroll
            for (int p = 0; p < 4; ++p) acc2[c][p] = 0.f;

#pragma unroll
        for (int ri = 0; ri < 2; ++ri) {
            if (ri < nr) {
                const int i = i0r + ri;
                float win[4][12];
#pragma unroll
                for (int c = 0; c < 4; ++c)
#pragma unroll
                    for (int e = 0; e < 4; ++e) {
                        win[c][e]     = W[ri][c][0][e];
                        win[c][e + 4] = W[ri][c][1][e];
                        win[c][e + 8] = W[ri][c][2][e];
                    }
#pragma unroll
                for (int jj = 0; jj < 7; ++jj) {
                    const f32x4 kw4 = *(const f32x4*)&kw_lds[(i * 7 + jj) * 64 + pg * 4];
#pragma unroll
                    for (int c = 0; c < 4; ++c)
#pragma unroll
                        for (int p = 0; p < 4; ++p)
                            acc2[c][p] += kw4[p] * win[c][p + jj + 1];
                }
            }
        }

        // store partials: pacc[w][lane][c], 20-word thread stride
#pragma unroll
        for (int c = 0; c < 4; ++c) {
            f32x4 st;
#pragma unroll
            for (int p = 0; p < 4; ++p) st[p] = acc2[c][p];
            *(f32x4*)&pacc[w * 1280 + lane * 20 + c * 4] = st;
        }
    }
    __syncthreads();

    // ---- Reduce: 256 threads, thread = (t = tid&63, c = tid>>6) ----
    {
        const int t = tid & 63;
        const int c = tid >> 6;
        const int base = t * 20 + c * 4;
        const f32x4 s0 = *(const f32x4*)&pacc[base];
        const f32x4 s1 = *(const f32x4*)&pacc[1280 + base];
        const f32x4 s2 = *(const f32x4*)&pacc[2560 + base];
        const f32x4 s3 = *(const f32x4*)&pacc[3840 + base];
        const f32x4 sum = s0 + s1 + s2 + s3;

        const int pg = t & 15;
        const int cq = t >> 4;
        const int hw4 = tile * 64 + pg * 4;
        *(f32x4*)(out + ((size_t)b * C_IN + g * GC + cq * 4 + c) * HW + hw4) = sum;
    }
}

extern "C" void kernel_launch(void* const* d_in, const int* in_sizes, int n_in,
                              void* d_out, int out_size, void* d_ws, size_t ws_size,
                              hipStream_t stream) {
    const float* x     = (const float*)d_in[0];
    const float* w1    = (const float*)d_in[1];
    const float* gamma = (const float*)d_in[2];
    const float* beta  = (const float*)d_in[3];
    const float* mean  = (const float*)d_in[4];
    const float* var   = (const float*)d_in[5];
    const float* w2    = (const float*)d_in[6];
    const float* b2    = (const float*)d_in[7];
    float* out = (float*)d_out;

    char* ws = (char*)d_ws;
    unsigned short* ybf   = (unsigned short*)(ws);             // 1,605,632 B
    unsigned short* wprep = (unsigned short*)(ws + 1605632);   //   131,072 B
    float*          b2pad = (float*)(ws + 1736704);            //     4,096 B
    unsigned short* w1bf  = (unsigned short*)(ws + 1740800);   //    32,768 B

    prep_kernel<<<dim3(256), dim3(256), 0, stream>>>(w1, w2, b2, w1bf, wprep, b2pad);
    conv1_bn_relu<<<dim3(196), dim3(256), 0, stream>>>(x, w1bf, gamma, beta, mean, var, ybf);
    conv2_involution<<<dim3(49, 64), dim3(256), 0, stream>>>(x, ybf, wprep, b2pad, out);
}

// Round 18
// 40.859 us; speedup vs baseline: 1.5671x; 1.1313x over previous
//
#include <hip/hip_runtime.h>

// Involution fused kernels for MI355X (gfx950).  (R11 champion, reverted)
// x: (4,256,56,56) f32, w1: (64,256), bn(64), w2: (784,64), b2: (784)
// out: (4,256,56,56) f32
// ws: ybf16 [4][3136][64] | wprep bf16 [16][64][64] | b2pad f32 [16][64] | w1bf bf16 [64][256]

#define HW    3136
#define WIDE  56
#define C_IN  256
#define CR    64
#define GC    16
#define KK    49
#define BN_EPS 1e-5f

typedef __attribute__((ext_vector_type(8))) short short8;
typedef __attribute__((ext_vector_type(4))) float f32x4;
typedef __attribute__((ext_vector_type(2))) unsigned int u32x2;

__device__ __forceinline__ unsigned short f2bf(float f) {
    unsigned u = __float_as_uint(f);
    return (unsigned short)((u + 0x7FFFu + ((u >> 16) & 1u)) >> 16);   // RNE
}

// ---- Prep: w1bf[o][c] bf16; wprep[g][k][c] bf16 (k>=49 zero); b2pad[g][k] f32 ----
__global__ __launch_bounds__(256) void prep_kernel(
    const float* __restrict__ w1, const float* __restrict__ w2,
    const float* __restrict__ b2,
    unsigned short* __restrict__ w1bf, unsigned short* __restrict__ wprep,
    float* __restrict__ b2pad)
{
    const int t = blockIdx.x * 256 + threadIdx.x;   // 0..65535
    if (t < 16384) {                                // w1bf: same [o][c] layout
        w1bf[t] = f2bf(w1[t]);
    }
    {                                               // wprep: g=t>>12, k=(t>>6)&63, c=t&63
        const int g = t >> 12, k = (t >> 6) & 63, c = t & 63;
        wprep[t] = (k < KK) ? f2bf(w2[(size_t)(g * KK + k) * CR + c]) : (unsigned short)0;
    }
    if (t < 1024) {                                 // b2pad
        const int g = t >> 6, k = t & 63;
        b2pad[t] = (k < KK) ? b2[g * KK + k] : 0.f;
    }
}

// LDS xs[px][c] bf16, XOR-swizzled: byte = (px*512 + c*2) ^ ((px&7)<<4).
__device__ __forceinline__ int xs_byte(int px, int c) {
    return ((px << 9) + (c << 1)) ^ ((px & 7) << 4);
}

// ---- Kernel 1: y = relu(bn(w1 @ x)) -> bf16 [b][px][c], via MFMA ----
__global__ __launch_bounds__(256) void conv1_bn_relu(
    const float* __restrict__ x, const unsigned short* __restrict__ w1bf,
    const float* __restrict__ gamma, const float* __restrict__ beta,
    const float* __restrict__ mean, const float* __restrict__ var,
    unsigned short* __restrict__ ybf)
{
    __shared__ unsigned short xs[64 * 256];   // 32 KB

    const int t    = threadIdx.x;
    const int lane = t & 63;
    const int q    = __builtin_amdgcn_readfirstlane(t >> 6);  // wave 0..3
    const int tile = blockIdx.x;              // 0..195
    const int b    = tile / 49;
    const int hw0  = (tile - b * 49) * 64;

    // ---- stage x[b][c][hw0+lane] -> xs[lane][c] ----
    {
        const int px = lane;
        const int cb = q * 64;
        const float* __restrict__ xb = x + ((size_t)b * C_IN + cb) * HW + hw0 + px;
#pragma unroll
        for (int i = 0; i < 8; ++i) {
            short8 pk;
#pragma unroll
            for (int j = 0; j < 8; ++j)
                pk[j] = (short)f2bf(xb[(size_t)(i * 8 + j) * HW]);
            *(short8*)((char*)xs + xs_byte(px, cb + i * 8)) = pk;
        }
    }
    __syncthreads();

    // ---- MFMA: y[o][px] for px-quadrant q ----
    const int l15 = lane & 15;
    const int lg  = lane >> 4;
    const int px  = q * 16 + l15;

    f32x4 acc[4];
#pragma unroll
    for (int mt = 0; mt < 4; ++mt) acc[mt] = (f32x4){0.f, 0.f, 0.f, 0.f};

#pragma unroll
    for (int kk = 0; kk < 8; ++kk) {
        const short8 Bf = *(const short8*)((const char*)xs + xs_byte(px, kk * 32 + lg * 8));
#pragma unroll
        for (int mt = 0; mt < 4; ++mt) {
            const short8 Af = *(const short8*)(w1bf + (mt * 16 + l15) * C_IN + kk * 32 + lg * 8);
            acc[mt] = __builtin_amdgcn_mfma_f32_16x16x32_bf16(Af, Bf, acc[mt], 0, 0, 0);
        }
    }

    // ---- BN + ReLU + pack; D: col=l15 -> px, row=lg*4+r -> o ----
#pragma unroll
    for (int mt = 0; mt < 4; ++mt) {
        const int o0 = mt * 16 + lg * 4;
        const f32x4 ga = *(const f32x4*)(gamma + o0);
        const f32x4 be = *(const f32x4*)(beta + o0);
        const f32x4 mn = *(const f32x4*)(mean + o0);
        const f32x4 va = *(const f32x4*)(var + o0);
        unsigned short o4[4];
#pragma unroll
        for (int r = 0; r < 4; ++r) {
            const float sc = ga[r] * rsqrtf(va[r] + BN_EPS);
            const float sh = be[r] - mn[r] * sc;
            o4[r] = f2bf(fmaxf(acc[mt][r] * sc + sh, 0.f));
        }
        u32x2 pk;
        pk.x = (unsigned)o4[0] | ((unsigned)o4[1] << 16);
        pk.y = (unsigned)o4[2] | ((unsigned)o4[3] << 16);
        *(u32x2*)(ybf + ((size_t)(b * HW + hw0 + px)) * 64 + o0) = pk;
    }
}

// ---- Kernel 2: MFMA conv2 + vectorized involution (R5 body). ----
__global__ __launch_bounds__(64) void conv2_involution(
    const float* __restrict__ x, const unsigned short* __restrict__ ybf,
    const unsigned short* __restrict__ wprep, const float* __restrict__ b2pad,
    float* __restrict__ out)
{
    __shared__ float kw_lds[64 * 64];   // [tap][px], 16 KB

    const int tid  = threadIdx.x;
    const int l15  = tid & 15;
    const int lg   = tid >> 4;
    const int tile = blockIdx.x;                 // 0..48
    const int g    = blockIdx.y & 15;
    const int b    = blockIdx.y >> 4;

    // ---- Phase 1: kw = W2g @ y  (per-pixel 64-tap kernels) ----
    {
        short8 Bf[4][2], Af[4][2];
#pragma unroll
        for (int ct = 0; ct < 4; ++ct) {
            const int hwp = tile * 64 + ct * 16 + l15;
            const unsigned short* yb = ybf + ((size_t)(b * HW + hwp)) * 64 + lg * 8;
            Bf[ct][0] = *(const short8*)(yb);
            Bf[ct][1] = *(const short8*)(yb + 32);
        }
#pragma unroll
        for (int rt = 0; rt < 4; ++rt) {
            const unsigned short* ar = wprep + g * 4096 + (rt * 16 + l15) * 64 + lg * 8;
            Af[rt][0] = *(const short8*)(ar);
            Af[rt][1] = *(const short8*)(ar + 32);
        }
        f32x4 acc[4][4];
#pragma unroll
        for (int ct = 0; ct < 4; ++ct)
#pragma unroll
            for (int rt = 0; rt < 4; ++rt) {
                acc[ct][rt] = (f32x4){0.f, 0.f, 0.f, 0.f};
                acc[ct][rt] = __builtin_amdgcn_mfma_f32_16x16x32_bf16(Af[rt][0], Bf[ct][0], acc[ct][rt], 0, 0, 0);
                acc[ct][rt] = __builtin_amdgcn_mfma_f32_16x16x32_bf16(Af[rt][1], Bf[ct][1], acc[ct][rt], 0, 0, 0);
            }

        float bias[4][4];
#pragma unroll
        for (int rt = 0; rt < 4; ++rt)
#pragma unroll
            for (int r = 0; r < 4; ++r)
                bias[rt][r] = b2pad[g * 64 + rt * 16 + lg * 4 + r];

#pragma unroll
        for (int ct = 0; ct < 4; ++ct) {
            const int pxc = ct * 16 + l15;
            const int hwp = tile * 64 + pxc;
            const int hp  = hwp / WIDE;
            const int wp  = hwp - hp * WIDE;
#pragma unroll
            for (int rt = 0; rt < 4; ++rt)
#pragma unroll
                for (int r = 0; r < 4; ++r) {
                    const int k  = rt * 16 + lg * 4 + r;
                    const int i7 = k / 7, j7 = k - i7 * 7;
                    const int rr = hp + i7 - 3, cc = wp + j7 - 3;
                    const bool valid = (k < KK) & (rr >= 0) & (rr < WIDE) &
                                       (cc >= 0) & (cc < WIDE);
                    kw_lds[k * 64 + pxc] = valid ? (acc[ct][rt][r] + bias[rt][r]) : 0.f;
                }
        }
    }
    __syncthreads();

    // ---- Phase 2: involution, 4 px x 4 ch per thread ----
    const int pg   = tid & 15;
    const int cq   = tid >> 4;
    const int hw4  = tile * 64 + pg * 4;         // 4-aligned flat pixel base
    const int hrow = hw4 / WIDE;
    const int hcol = hw4 - hrow * WIDE;          // 4-aligned (56 % 4 == 0)

    const float* bp[4];
#pragma unroll
    for (int c = 0; c < 4; ++c)
        bp[c] = x + ((size_t)b * C_IN + g * GC + cq * 4 + c) * HW;

    float acc2[4][4];   // [ch][px]
#pragma unroll
    for (int c = 0; c < 4; ++c)
#pragma unroll
        for (int p = 0; p < 4; ++p) acc2[c][p] = 0.f;

#pragma unroll
    for (int i = 0; i < 7; ++i) {
        const int rc    = min(max(hrow + i - 3, 0), WIDE - 1);  // v_med3
        const int basef = rc * WIDE + hcol;
        const int i0 = max(basef - 4, 0);
        const int i2 = min(basef + 4, HW - 4);

        float win[4][12];
#pragma unroll
        for (int c = 0; c < 4; ++c) {
            const f32x4 A0 = *(const f32x4*)(bp[c] + i0);
            const f32x4 A1 = *(const f32x4*)(bp[c] + basef);
            const f32x4 A2 = *(const f32x4*)(bp[c] + i2);
#pragma unroll
            for (int e = 0; e < 4; ++e) {
                win[c][e]     = A0[e];
                win[c][e + 4] = A1[e];
                win[c][e + 8] = A2[e];
            }
        }
#pragma unroll
        for (int jj = 0; jj < 7; ++jj) {
            const f32x4 kw4 = *(const f32x4*)&kw_lds[(i * 7 + jj) * 64 + pg * 4];
#pragma unroll
            for (int c = 0; c < 4; ++c)
#pragma unroll
                for (int p = 0; p < 4; ++p)
                    acc2[c][p] += kw4[p] * win[c][p + jj + 1];   // e = 4+(p+jj-3)
        }
    }

#pragma unroll
    for (int c = 0; c < 4; ++c) {
        f32x4 st;
#pragma unroll
        for (int p = 0; p < 4; ++p) st[p] = acc2[c][p];
        *(f32x4*)(out + ((size_t)b * C_IN + g * GC + cq * 4 + c) * HW + hw4) = st;
    }
}

extern "C" void kernel_launch(void* const* d_in, const int* in_sizes, int n_in,
                              void* d_out, int out_size, void* d_ws, size_t ws_size,
                              hipStream_t stream) {
    const float* x     = (const float*)d_in[0];
    const float* w1    = (const float*)d_in[1];
    const float* gamma = (const float*)d_in[2];
    const float* beta  = (const float*)d_in[3];
    const float* mean  = (const float*)d_in[4];
    const float* var   = (const float*)d_in[5];
    const float* w2    = (const float*)d_in[6];
    const float* b2    = (const float*)d_in[7];
    float* out = (float*)d_out;

    char* ws = (char*)d_ws;
    unsigned short* ybf   = (unsigned short*)(ws);             // 1,605,632 B
    unsigned short* wprep = (unsigned short*)(ws + 1605632);   //   131,072 B
    float*          b2pad = (float*)(ws + 1736704);            //     4,096 B
    unsigned short* w1bf  = (unsigned short*)(ws + 1740800);   //    32,768 B

    prep_kernel<<<dim3(256), dim3(256), 0, stream>>>(w1, w2, b2, w1bf, wprep, b2pad);
    conv1_bn_relu<<<dim3(196), dim3(256), 0, stream>>>(x, w1bf, gamma, beta, mean, var, ybf);
    conv2_involution<<<dim3(49, 64), dim3(64), 0, stream>>>(x, ybf, wprep, b2pad, out);
}